// Round 1
// baseline (5959.472 us; speedup 1.0000x reference)
//
#include <hip/hip_runtime.h>
#include <cstdint>
#include <cstddef>

// ---------------- problem constants ----------------
#define CD    512          // channels
#define NHEAD 8
#define HD    64           // head dim
#define C1D   358
#define C2D   154
#define BB    8            // batch
#define PP    4096         // h*w
#define NT    32768        // PP*BB tokens
#define LKK   256          // kv length (both attentions)

// ---------------- transpose x (b,c,p) -> Xt[(p*8+b)*512+c] ----------------
__global__ __launch_bounds__(256)
void transpose_x(const float* __restrict__ x, float* __restrict__ Xt) {
    __shared__ float tile[32][33];
    const int b  = blockIdx.z;
    const int p0 = blockIdx.x << 5;
    const int c0 = blockIdx.y << 5;
    const int tx = threadIdx.x;   // 32
    const int ty = threadIdx.y;   // 8
#pragma unroll
    for (int i = 0; i < 4; i++) {
        int c = c0 + ty + (i << 3);
        tile[ty + (i << 3)][tx] = x[((size_t)b * CD + c) * PP + p0 + tx];
    }
    __syncthreads();
#pragma unroll
    for (int i = 0; i < 4; i++) {
        int p = p0 + ty + (i << 3);
        int c = c0 + tx;
        Xt[((size_t)p * BB + b) * CD + c] = tile[tx][ty + (i << 3)];
    }
}

// ------- x (b,c,p) -> Xv[t'*512+c], t' = (hh*4+wd)*128 + b*16 + nw -------
__global__ __launch_bounds__(256)
void make_xv(const float* __restrict__ x, float* __restrict__ Xv) {
    __shared__ float tile[32][33];
    const int b  = blockIdx.z;
    const int p0 = blockIdx.x << 5;
    const int c0 = blockIdx.y << 5;
    const int tx = threadIdx.x;
    const int ty = threadIdx.y;
#pragma unroll
    for (int i = 0; i < 4; i++) {
        int c = c0 + ty + (i << 3);
        tile[ty + (i << 3)][tx] = x[((size_t)b * CD + c) * PP + p0 + tx];
    }
    __syncthreads();
#pragma unroll
    for (int i = 0; i < 4; i++) {
        int p  = p0 + ty + (i << 3);
        int c  = c0 + tx;
        int hh = p >> 6, ww = p & 63;
        int nw = ww >> 2, wd = ww & 3;
        int tp = ((hh << 2) + wd) * 128 + (b << 4) + nw;
        Xv[(size_t)tp * CD + c] = tile[tx][ty + (i << 3)];
    }
}

// ---- pool from Xt: Xp[(b*256+k)*512+c] = mean 4x4 window, k=ph*16+pw ----
__global__ __launch_bounds__(512)
void pool_from_xt(const float* __restrict__ Xt, float* __restrict__ Xp) {
    const int u = blockIdx.x;          // b*256+k
    const int c = threadIdx.x;         // 512
    const int b = u >> 8, k = u & 255;
    const int ph = k >> 4, pw = k & 15;
    float s = 0.f;
#pragma unroll
    for (int dy = 0; dy < 4; dy++)
#pragma unroll
        for (int dx = 0; dx < 4; dx++) {
            int p = ((ph << 2) + dy) * 64 + (pw << 2) + dx;
            s += Xt[((size_t)p * BB + b) * CD + c];
        }
    Xp[(size_t)u * CD + c] = s * (1.f / 16.f);
}

// --------------- GEMM: C[m][n] = sum_k A[m][k]*W[n][k] + bias[n] ---------------
// 128x128 tile, BK=16, 256 threads, 8x8 micro-tile.
__global__ __launch_bounds__(256)
void gemm_bias(const float* __restrict__ A, const float* __restrict__ W,
               const float* __restrict__ bias, float* __restrict__ Cout,
               int M, int N, int K) {
    __shared__ float As[16][132];
    __shared__ float Ws[16][132];
    const int tid = threadIdx.x;
    const int tx = tid & 15;          // n group
    const int ty = tid >> 4;          // m group
    const int row0 = blockIdx.y << 7;
    const int col0 = blockIdx.x << 7;
    const int kk = tid & 15;
    const int mm = tid >> 4;

    float acc[8][8];
#pragma unroll
    for (int i = 0; i < 8; i++)
#pragma unroll
        for (int j = 0; j < 8; j++) acc[i][j] = 0.f;

    for (int k0 = 0; k0 < K; k0 += 16) {
#pragma unroll
        for (int i = 0; i < 8; i++) {
            int m  = mm + (i << 4);
            int gm = row0 + m;
            As[kk][m] = (gm < M) ? A[(size_t)gm * K + k0 + kk] : 0.f;
            int gn = col0 + m;
            Ws[kk][m] = (gn < N) ? W[(size_t)gn * K + k0 + kk] : 0.f;
        }
        __syncthreads();
#pragma unroll
        for (int kt = 0; kt < 16; kt++) {
            const float4 a0 = *reinterpret_cast<const float4*>(&As[kt][ty * 8]);
            const float4 a1 = *reinterpret_cast<const float4*>(&As[kt][ty * 8 + 4]);
            const float4 b0 = *reinterpret_cast<const float4*>(&Ws[kt][tx * 8]);
            const float4 b1 = *reinterpret_cast<const float4*>(&Ws[kt][tx * 8 + 4]);
            float a[8] = {a0.x, a0.y, a0.z, a0.w, a1.x, a1.y, a1.z, a1.w};
            float bv[8] = {b0.x, b0.y, b0.z, b0.w, b1.x, b1.y, b1.z, b1.w};
#pragma unroll
            for (int i = 0; i < 8; i++)
#pragma unroll
                for (int j = 0; j < 8; j++) acc[i][j] += a[i] * bv[j];
        }
        __syncthreads();
    }
#pragma unroll
    for (int i = 0; i < 8; i++) {
        int gm = row0 + ty * 8 + i;
        if (gm < M) {
#pragma unroll
            for (int j = 0; j < 8; j++) {
                int gn = col0 + tx * 8 + j;
                if (gn < N) Cout[(size_t)gm * N + gn] = acc[i][j] + bias[gn];
            }
        }
    }
}

// ---------------- fused attention (Lk = 256, D = 64) ----------------
// row(q,batch) = q*QT + batch*QB ; row(k,batch) = k*KT + batch*KB
// K,V for one (batch,head) staged in LDS; one wave processes one q row.
__device__ __forceinline__ float lane_bcast(float v, int src) {
    return __int_as_float(__builtin_amdgcn_readlane(__float_as_int(v), src));
}

__global__ __launch_bounds__(256)
void attn_fused(const float* __restrict__ Q, const float* __restrict__ Kp,
                const float* __restrict__ Vp, float* __restrict__ O,
                int rowsPerBlock, int QT, int QB, int KT, int KB) {
    __shared__ float Kt[64][LKK + 1];   // transposed K: [d][k]
    __shared__ float Vs[LKK][64];       // [k][d]
    const int tid  = threadIdx.x;
    const int lane = tid & 63;
    const int wid  = tid >> 6;
    const int bh = blockIdx.y;
    const int bi = bh >> 3;            // batch index
    const int h  = bh & 7;             // head

    for (int idx = tid; idx < LKK * 64; idx += 256) {
        int k = idx >> 6, d = idx & 63;
        size_t krow = (size_t)k * KT + (size_t)bi * KB;
        float kvv = Kp[krow * CD + h * HD + d];
        float vvv = Vp[krow * CD + h * HD + d];
        Kt[d][k] = kvv;
        Vs[k][d] = vvv;
    }
    __syncthreads();

    const int q0 = blockIdx.x * rowsPerBlock;
    for (int q = q0 + wid; q < q0 + rowsPerBlock; q += 4) {
        size_t qrow = (size_t)q * QT + (size_t)bi * QB;
        float qv = Q[qrow * CD + h * HD + lane];
        float s[4] = {0.f, 0.f, 0.f, 0.f};
        for (int d = 0; d < 64; d++) {
            float qd = lane_bcast(qv, d);
#pragma unroll
            for (int j = 0; j < 4; j++) s[j] += qd * Kt[d][lane + (j << 6)];
        }
#pragma unroll
        for (int j = 0; j < 4; j++) s[j] *= 0.125f;   // 1/sqrt(64)
        // softmax over 256 (4 per lane x 64 lanes)
        float m = fmaxf(fmaxf(s[0], s[1]), fmaxf(s[2], s[3]));
        for (int off = 32; off; off >>= 1) m = fmaxf(m, __shfl_xor(m, off));
        float p[4], sum = 0.f;
#pragma unroll
        for (int j = 0; j < 4; j++) { p[j] = __expf(s[j] - m); sum += p[j]; }
        for (int off = 32; off; off >>= 1) sum += __shfl_xor(sum, off);
        float rinv = 1.f / sum;
#pragma unroll
        for (int j = 0; j < 4; j++) p[j] *= rinv;
        // PV
        float o = 0.f;
        for (int src = 0; src < 64; src++) {
#pragma unroll
            for (int j = 0; j < 4; j++) {
                float pk = lane_bcast(p[j], src);
                o += pk * Vs[(j << 6) + src][lane];
            }
        }
        O[qrow * CD + h * HD + lane] = o;
    }
}

// ------------- permute vertical out rows t'(s,bb) -> t(p,b) -------------
__global__ __launch_bounds__(512)
void permute_va(const float* __restrict__ VOX, float* __restrict__ vax) {
    const int t = blockIdx.x;          // t = p*8+b
    const int c = threadIdx.x;
    const int p = t >> 3, b = t & 7;
    const int hh = p >> 6, ww = p & 63;
    const int nw = ww >> 2, wd = ww & 3;
    const int tp = ((hh << 2) + wd) * 128 + (b << 4) + nw;
    vax[(size_t)t * CD + c] = VOX[(size_t)tp * CD + c];
}

// ------ concat [HA|VA] -> attn_bchw + partial sums of res = attn + x ------
__global__ __launch_bounds__(256)
void concat_stats(const float* __restrict__ HA, const float* __restrict__ VA,
                  const float* __restrict__ x, float* __restrict__ attn_out,
                  float* __restrict__ stats) {
    __shared__ float tile[32][33];
    const int b  = blockIdx.z;
    const int p0 = blockIdx.x << 5;
    const int c0 = blockIdx.y << 5;
    const int tx = threadIdx.x;   // 32
    const int ty = threadIdx.y;   // 8
#pragma unroll
    for (int i = 0; i < 4; i++) {
        int c = c0 + tx;
        int p = p0 + ty + (i << 3);
        size_t t = (size_t)p * BB + b;
        float v = (c < C1D) ? HA[t * C1D + c] : VA[t * C2D + (c - C1D)];
        tile[ty + (i << 3)][tx] = v;
    }
    __syncthreads();
    float lsum = 0.f, lsq = 0.f;
#pragma unroll
    for (int i = 0; i < 4; i++) {
        int c = c0 + ty + (i << 3);
        int p = p0 + tx;
        size_t o = ((size_t)b * CD + c) * PP + p;
        float v = tile[tx][ty + (i << 3)];
        attn_out[o] = v;
        float r = v + x[o];
        lsum += r; lsq += r * r;
    }
    for (int off = 32; off; off >>= 1) {
        lsum += __shfl_xor(lsum, off);
        lsq  += __shfl_xor(lsq, off);
    }
    __shared__ float wsum[4], wsq[4];
    const int tl = ty * 32 + tx;
    if ((tl & 63) == 0) { wsum[tl >> 6] = lsum; wsq[tl >> 6] = lsq; }
    __syncthreads();
    if (tl == 0) {
        atomicAdd(&stats[b],     wsum[0] + wsum[1] + wsum[2] + wsum[3]);
        atomicAdd(&stats[8 + b], wsq[0] + wsq[1] + wsq[2] + wsq[3]);
    }
}

__global__ void stats_final(float* stats) {
    int b = threadIdx.x;
    if (b < 8) {
        const float n = (float)CD * (float)PP;
        float mu  = stats[b] / n;
        float var = stats[8 + b] / n - mu * mu;
        stats[16 + b] = mu;
        stats[24 + b] = 1.f / sqrtf(var + 1e-5f);
    }
}

__global__ __launch_bounds__(256)
void norm_kernel(const float* __restrict__ attn, const float* __restrict__ x,
                 const float* __restrict__ stats, float* __restrict__ out) {
    size_t i = ((size_t)blockIdx.x * blockDim.x + threadIdx.x) * 4;
    int b = (int)(i >> 21);            // 512*4096 = 2^21 elements per batch
    float mu  = stats[16 + b];
    float inv = stats[24 + b];
    const float4 a4 = *reinterpret_cast<const float4*>(attn + i);
    const float4 x4 = *reinterpret_cast<const float4*>(x + i);
    float4 r;
    r.x = (a4.x + x4.x - mu) * inv;
    r.y = (a4.y + x4.y - mu) * inv;
    r.z = (a4.z + x4.z - mu) * inv;
    r.w = (a4.w + x4.w - mu) * inv;
    *reinterpret_cast<float4*>(out + i) = r;
}

// ---------------- host launch ----------------
extern "C" void kernel_launch(void* const* d_in, const int* in_sizes, int n_in,
                              void* d_out, int out_size, void* d_ws, size_t ws_size,
                              hipStream_t stream) {
    const float* x     = (const float*)d_in[0];
    const float* hinw  = (const float*)d_in[1];
    const float* hinb  = (const float*)d_in[2];
    const float* houtw = (const float*)d_in[3];
    const float* houtb = (const float*)d_in[4];
    const float* vinw  = (const float*)d_in[5];
    const float* vinb  = (const float*)d_in[6];
    const float* voutw = (const float*)d_in[7];
    const float* voutb = (const float*)d_in[8];
    const float* hfcw  = (const float*)d_in[9];
    const float* hfcb  = (const float*)d_in[10];
    const float* vfcw  = (const float*)d_in[11];
    const float* vfcb  = (const float*)d_in[12];

    float* ws  = (float*)d_ws;
    float* WS0 = ws;                         // 16,777,216  Xt -> OH -> Xv -> OV
    float* WS1 = ws + 16777216;              // 16,777,216  QH -> QV -> VOX
    float* WS2 = ws + 33554432;              // 11,730,944  HA
    float* WS3 = ws + 45285376;              //  5,046,272  VA
    float* XP  = ws + 50331648;              //  1,048,576
    float* KH  = ws + 51380224;              //  1,048,576
    float* VH  = ws + 52428800;              //  1,048,576
    float* STATS = ws + 53477376;            //  32 floats

    float* out_res = (float*)d_out;          // result
    float* out_hax = out_res + 16777216;     // ha_x
    float* out_vax = out_res + 33554432;     // va_x
    float* out_att = out_res + 50331648;     // attn_bchw
    // out_att doubles as KV scratch, out_res as VV scratch (both dead before
    // their final producers run).

    const dim3 tb(32, 8, 1);
    const dim3 tgrid(128, 16, 8);

    hipMemsetAsync(STATS, 0, 32 * sizeof(float), stream);

    // ---- horizontal branch ----
    transpose_x<<<tgrid, tb, 0, stream>>>(x, WS0);                       // Xt
    pool_from_xt<<<2048, 512, 0, stream>>>(WS0, XP);                     // pooled kv tokens
    gemm_bias<<<dim3(4, 256), 256, 0, stream>>>(WS0, hinw, hinb, WS1, NT, CD, CD);            // QH
    gemm_bias<<<dim3(4, 16), 256, 0, stream>>>(XP, hinw + CD * CD, hinb + CD, KH, 2048, CD, CD);   // KH
    gemm_bias<<<dim3(4, 16), 256, 0, stream>>>(XP, hinw + 2 * CD * CD, hinb + 2 * CD, VH, 2048, CD, CD); // VH
    attn_fused<<<dim3(8, 64), 256, 0, stream>>>(WS1, KH, VH, WS0, 512, BB, 1, 1, 256);        // OH -> WS0
    gemm_bias<<<dim3(4, 256), 256, 0, stream>>>(WS0, houtw, houtb, out_hax, NT, CD, CD);      // ha_x
    gemm_bias<<<dim3(3, 256), 256, 0, stream>>>(out_hax, hfcw, hfcb, WS2, NT, C1D, CD);       // HA

    // ---- vertical branch ----
    make_xv<<<tgrid, tb, 0, stream>>>(x, WS0);                           // Xv
    gemm_bias<<<dim3(4, 256), 256, 0, stream>>>(WS0, vinw, vinb, WS1, NT, CD, CD);            // QV
    gemm_bias<<<dim3(4, 256), 256, 0, stream>>>(WS0, vinw + CD * CD, vinb + CD, out_att, NT, CD, CD);   // KV
    gemm_bias<<<dim3(4, 256), 256, 0, stream>>>(WS0, vinw + 2 * CD * CD, vinb + 2 * CD, out_res, NT, CD, CD); // VV
    attn_fused<<<dim3(4, 1024), 256, 0, stream>>>(WS1, out_att, out_res, WS0, 64, 128, 1, 128, 1);      // OV -> WS0
    gemm_bias<<<dim3(4, 256), 256, 0, stream>>>(WS0, voutw, voutb, WS1, NT, CD, CD);          // VOX (t' order)
    permute_va<<<NT, 512, 0, stream>>>(WS1, out_vax);                    // va_x (t order)
    gemm_bias<<<dim3(2, 256), 256, 0, stream>>>(out_vax, vfcw, vfcb, WS3, NT, C2D, CD);       // VA

    // ---- concat + residual + layernorm ----
    concat_stats<<<tgrid, tb, 0, stream>>>(WS2, WS3, x, out_att, STATS);
    stats_final<<<1, 8, 0, stream>>>(STATS);
    norm_kernel<<<16384, 256, 0, stream>>>(out_att, x, STATS, out_res);
}

// Round 3
// 1333.521 us; speedup vs baseline: 4.4690x; 4.4690x over previous
//
#include <hip/hip_runtime.h>
#include <cstdint>
#include <cstddef>

// ---------------- problem constants ----------------
#define CD    512
#define HD    64
#define C1D   358
#define C2D   154
#define BB    8
#define PP    4096
#define NT    32768
#define LKK   256

typedef __attribute__((ext_vector_type(8))) short bf16x8;
typedef __attribute__((ext_vector_type(4))) float f32x4;

__device__ __forceinline__ unsigned short f2bf(float f) {
    union { float f; unsigned u; } v; v.f = f;
    unsigned r = v.u + 0x7FFF + ((v.u >> 16) & 1);
    return (unsigned short)(r >> 16);
}
__device__ __forceinline__ float bf2f(unsigned short s) {
    union { unsigned u; float f; } v; v.u = ((unsigned)s) << 16;
    return v.f;
}

#define GL_LDS16(gp, lp) __builtin_amdgcn_global_load_lds( \
    (const __attribute__((address_space(1))) unsigned int*)(gp), \
    (__attribute__((address_space(3))) unsigned int*)(lp), 16, 0, 0)

// ---------------- weight casts ----------------
__global__ __launch_bounds__(256)
void cast_w(const float* __restrict__ src, unsigned short* __restrict__ dst, int n) {
    int i = blockIdx.x * 256 + threadIdx.x;
    if (i < n) dst[i] = f2bf(src[i]);
}

// pad [Nreal][K] -> [Npad][K], zero-filled rows >= Nreal
__global__ __launch_bounds__(256)
void pad_w(const float* __restrict__ src, unsigned short* __restrict__ dst,
           int Nreal, int Npad, int K) {
    int i = blockIdx.x * 256 + threadIdx.x;
    if (i < Npad * K) {
        int r = i / K, c = i - r * K;
        dst[i] = (r < Nreal) ? f2bf(src[(size_t)r * K + c]) : 0;
    }
}

// -------- transpose x (b,c,p) -> Xt[(p*8+b)*512+c] (bf16) --------
__global__ __launch_bounds__(256)
void transpose_x(const float* __restrict__ x, unsigned short* __restrict__ Xt) {
    __shared__ float tile[32][33];
    const int b  = blockIdx.z;
    const int p0 = blockIdx.x << 5;
    const int c0 = blockIdx.y << 5;
    const int tx = threadIdx.x;   // 32
    const int ty = threadIdx.y;   // 8
#pragma unroll
    for (int i = 0; i < 4; i++) {
        int c = c0 + ty + (i << 3);
        tile[ty + (i << 3)][tx] = x[((size_t)b * CD + c) * PP + p0 + tx];
    }
    __syncthreads();
#pragma unroll
    for (int i = 0; i < 4; i++) {
        int p = p0 + ty + (i << 3);
        Xt[((size_t)p * BB + b) * CD + c0 + tx] = f2bf(tile[tx][ty + (i << 3)]);
    }
}

// ---- x (b,c,p) -> Xv[t'*512+c] bf16, t' = (hh*4+wd)*128 + b*16 + nw ----
__global__ __launch_bounds__(256)
void make_xv(const float* __restrict__ x, unsigned short* __restrict__ Xv) {
    __shared__ float tile[32][33];
    const int b  = blockIdx.z;
    const int p0 = blockIdx.x << 5;
    const int c0 = blockIdx.y << 5;
    const int tx = threadIdx.x;
    const int ty = threadIdx.y;
#pragma unroll
    for (int i = 0; i < 4; i++) {
        int c = c0 + ty + (i << 3);
        tile[ty + (i << 3)][tx] = x[((size_t)b * CD + c) * PP + p0 + tx];
    }
    __syncthreads();
#pragma unroll
    for (int i = 0; i < 4; i++) {
        int p  = p0 + ty + (i << 3);
        int hh = p >> 6, ww = p & 63;
        int nw = ww >> 2, wd = ww & 3;
        int tp = ((hh << 2) + wd) * 128 + (b << 4) + nw;
        Xv[(size_t)tp * CD + c0 + tx] = f2bf(tile[tx][ty + (i << 3)]);
    }
}

// ---- pool: Xp[(b*256+k)*512+c] = mean of 4x4 window (bf16 in/out) ----
__global__ __launch_bounds__(512)
void pool_from_xt(const unsigned short* __restrict__ Xt, unsigned short* __restrict__ Xp) {
    const int u = blockIdx.x;          // b*256+k
    const int c = threadIdx.x;         // 512
    const int b = u >> 8, k = u & 255;
    const int ph = k >> 4, pw = k & 15;
    float s = 0.f;
#pragma unroll
    for (int dy = 0; dy < 4; dy++)
#pragma unroll
        for (int dx = 0; dx < 4; dx++) {
            int p = ((ph << 2) + dy) * 64 + (pw << 2) + dx;
            s += bf2f(Xt[((size_t)p * BB + b) * CD + c]);
        }
    Xp[(size_t)u * CD + c] = f2bf(s * (1.f / 16.f));
}

// ---------------- MFMA GEMM ----------------
// C[m][n] = sum_k A[m][k]*W[n][k] + bias[n]; A [M][K] bf16, W [Npad][K] bf16.
// 128x128 tile, BK=64, 256 threads (4 waves 2x2), double-buffered LDS,
// global_load_lds width-16 staging. Optional fp32 and bf16 outputs.
__device__ __forceinline__ void stage_tile(const unsigned short* __restrict__ g,
                                           unsigned short* l, int K, int tid) {
#pragma unroll
    for (int i = 0; i < 4; i++) {
        int c  = i * 256 + tid;           // 16B chunk id, 0..1023
        int r  = c >> 3;                  // row 0..127
        int ko = (c & 7) << 3;            // k offset 0..56
        GL_LDS16(g + (size_t)r * K + ko, l + c * 8);
    }
}

__global__ __launch_bounds__(256)
void gemm_mfma(const unsigned short* __restrict__ A, const unsigned short* __restrict__ W,
               const float* __restrict__ bias,
               float* __restrict__ Cf, unsigned short* __restrict__ Cb,
               int M, int K, int Nreal) {
    __shared__ unsigned short ldsA[2][128][64];
    __shared__ unsigned short ldsB[2][128][64];
    const int tid  = threadIdx.x;
    const int lane = tid & 63;
    const int wid  = tid >> 6;
    const int wr = wid >> 1, wc = wid & 1;
    const int lr = lane & 15, lg = lane >> 4;
    const int row0 = blockIdx.y << 7;
    const int col0 = blockIdx.x << 7;

    f32x4 zero = {0.f, 0.f, 0.f, 0.f};
    f32x4 acc[4][4];
#pragma unroll
    for (int m = 0; m < 4; m++)
#pragma unroll
        for (int n = 0; n < 4; n++) acc[m][n] = zero;

    const unsigned short* Ab = A + (size_t)row0 * K;
    const unsigned short* Wb = W + (size_t)col0 * K;

    stage_tile(Ab, &ldsA[0][0][0], K, tid);
    stage_tile(Wb, &ldsB[0][0][0], K, tid);
    __syncthreads();

    const int NTILES = K >> 6;
    int buf = 0;
    for (int t = 0; t < NTILES; t++) {
        if (t + 1 < NTILES) {
            stage_tile(Ab + ((t + 1) << 6), &ldsA[buf ^ 1][0][0], K, tid);
            stage_tile(Wb + ((t + 1) << 6), &ldsB[buf ^ 1][0][0], K, tid);
        }
#pragma unroll
        for (int kk = 0; kk < 2; kk++) {
            bf16x8 af[4], bfr[4];
#pragma unroll
            for (int m = 0; m < 4; m++)
                af[m] = *reinterpret_cast<const bf16x8*>(&ldsA[buf][wr * 64 + m * 16 + lr][kk * 32 + lg * 8]);
#pragma unroll
            for (int n = 0; n < 4; n++)
                bfr[n] = *reinterpret_cast<const bf16x8*>(&ldsB[buf][wc * 64 + n * 16 + lr][kk * 32 + lg * 8]);
#pragma unroll
            for (int m = 0; m < 4; m++)
#pragma unroll
                for (int n = 0; n < 4; n++)
                    acc[m][n] = __builtin_amdgcn_mfma_f32_16x16x32_bf16(af[m], bfr[n], acc[m][n], 0, 0, 0);
        }
        __syncthreads();
        buf ^= 1;
    }

    // epilogue
#pragma unroll
    for (int n = 0; n < 4; n++) {
        int col = col0 + wc * 64 + n * 16 + lr;
        bool cok = col < Nreal;
        float bv = cok ? bias[col] : 0.f;
#pragma unroll
        for (int m = 0; m < 4; m++) {
            int row = row0 + wr * 64 + m * 16 + lg * 4;
            if (cok) {
#pragma unroll
                for (int i = 0; i < 4; i++) {
                    float v = acc[m][n][i] + bv;
                    if (Cf) Cf[(size_t)(row + i) * Nreal + col] = v;
                    if (Cb) Cb[(size_t)(row + i) * Nreal + col] = f2bf(v);
                }
            }
        }
    }
}

// ---------------- MFMA fused attention (Lk=256, D=64) ----------------
// token row address = q*QT + bi*QB (Q/O), k*KT + bi*KB (K/V); all bf16 [*][512]
// block: 512 threads = 8 waves; each wave owns 16 q-rows. O may alias Q.
__global__ __launch_bounds__(512)
void attn_mfma(const unsigned short* __restrict__ Q, const unsigned short* __restrict__ Kp,
               const unsigned short* __restrict__ Vp, unsigned short* __restrict__ O,
               int QT, int QB, int KT, int KB) {
    __shared__ unsigned short Kb[256][72];    // [k][d], +8 pad
    __shared__ unsigned short Vt[64][264];    // [d][k], +8 pad
    __shared__ unsigned short Pl[8][16][264]; // per-wave P tile
    const int tid  = threadIdx.x;
    const int lane = tid & 63;
    const int w    = tid >> 6;
    const int lr = lane & 15, lg = lane >> 4;
    const int bh = blockIdx.y, bi = bh >> 3, h = bh & 7;
    const int q0 = blockIdx.x << 7;

    // stage K and V^T
    for (int idx = tid; idx < 8192; idx += 512) {
        int k  = idx >> 5;
        int d2 = (idx & 31) << 1;
        size_t grow = ((size_t)k * KT + (size_t)bi * KB) * CD + h * HD + d2;
        unsigned int kv = *reinterpret_cast<const unsigned int*>(&Kp[grow]);
        unsigned int vv = *reinterpret_cast<const unsigned int*>(&Vp[grow]);
        Kb[k][d2]     = (unsigned short)(kv & 0xffff);
        Kb[k][d2 + 1] = (unsigned short)(kv >> 16);
        Vt[d2][k]     = (unsigned short)(vv & 0xffff);
        Vt[d2 + 1][k] = (unsigned short)(vv >> 16);
    }
    __syncthreads();

    // Q fragments (held in regs; enables in-place O)
    const int qrow = q0 + w * 16 + lr;
    const size_t qbase = ((size_t)qrow * QT + (size_t)bi * QB) * CD + h * HD;
    bf16x8 qf0 = *reinterpret_cast<const bf16x8*>(&Q[qbase + lg * 8]);
    bf16x8 qf1 = *reinterpret_cast<const bf16x8*>(&Q[qbase + 32 + lg * 8]);

    // S = Q K^T  (16 col-tiles of 16)
    f32x4 zero = {0.f, 0.f, 0.f, 0.f};
    f32x4 sacc[16];
#pragma unroll
    for (int t = 0; t < 16; t++) sacc[t] = zero;
#pragma unroll
    for (int t = 0; t < 16; t++) {
        bf16x8 kb0 = *reinterpret_cast<const bf16x8*>(&Kb[t * 16 + lr][lg * 8]);
        bf16x8 kb1 = *reinterpret_cast<const bf16x8*>(&Kb[t * 16 + lr][32 + lg * 8]);
        sacc[t] = __builtin_amdgcn_mfma_f32_16x16x32_bf16(qf0, kb0, sacc[t], 0, 0, 0);
        sacc[t] = __builtin_amdgcn_mfma_f32_16x16x32_bf16(qf1, kb1, sacc[t], 0, 0, 0);
    }
#pragma unroll
    for (int t = 0; t < 16; t++) sacc[t] = sacc[t] * 0.125f;

    // softmax over 256 cols; lane holds rows lg*4+i, cols t*16+lr
    float mrow[4] = {-1e30f, -1e30f, -1e30f, -1e30f};
#pragma unroll
    for (int t = 0; t < 16; t++)
#pragma unroll
        for (int i = 0; i < 4; i++) mrow[i] = fmaxf(mrow[i], sacc[t][i]);
#pragma unroll
    for (int i = 0; i < 4; i++) {
        mrow[i] = fmaxf(mrow[i], __shfl_xor(mrow[i], 1));
        mrow[i] = fmaxf(mrow[i], __shfl_xor(mrow[i], 2));
        mrow[i] = fmaxf(mrow[i], __shfl_xor(mrow[i], 4));
        mrow[i] = fmaxf(mrow[i], __shfl_xor(mrow[i], 8));
    }
    float ssum[4] = {0.f, 0.f, 0.f, 0.f};
#pragma unroll
    for (int t = 0; t < 16; t++)
#pragma unroll
        for (int i = 0; i < 4; i++) {
            float p = __expf(sacc[t][i] - mrow[i]);
            sacc[t][i] = p;
            ssum[i] += p;
        }
#pragma unroll
    for (int i = 0; i < 4; i++) {
        ssum[i] += __shfl_xor(ssum[i], 1);
        ssum[i] += __shfl_xor(ssum[i], 2);
        ssum[i] += __shfl_xor(ssum[i], 4);
        ssum[i] += __shfl_xor(ssum[i], 8);
    }
    float rinv[4];
#pragma unroll
    for (int i = 0; i < 4; i++) rinv[i] = 1.f / ssum[i];

    // write P (bf16) to this wave's LDS tile
#pragma unroll
    for (int t = 0; t < 16; t++)
#pragma unroll
        for (int i = 0; i < 4; i++)
            Pl[w][lg * 4 + i][t * 16 + lr] = f2bf(sacc[t][i] * rinv[i]);

    // O = P V  (4 d-tiles of 16, 8 k-steps of 32)
    f32x4 oacc[4];
#pragma unroll
    for (int n = 0; n < 4; n++) oacc[n] = zero;
#pragma unroll
    for (int ks = 0; ks < 8; ks++) {
        bf16x8 pa = *reinterpret_cast<const bf16x8*>(&Pl[w][lr][ks * 32 + lg * 8]);
#pragma unroll
        for (int n = 0; n < 4; n++) {
            bf16x8 vb = *reinterpret_cast<const bf16x8*>(&Vt[n * 16 + lr][ks * 32 + lg * 8]);
            oacc[n] = __builtin_amdgcn_mfma_f32_16x16x32_bf16(pa, vb, oacc[n], 0, 0, 0);
        }
    }
#pragma unroll
    for (int n = 0; n < 4; n++)
#pragma unroll
        for (int i = 0; i < 4; i++) {
            int qr2 = q0 + w * 16 + lg * 4 + i;
            size_t ob = ((size_t)qr2 * QT + (size_t)bi * QB) * CD + h * HD + n * 16 + lr;
            O[ob] = f2bf(oacc[n][i]);
        }
}

// ---- permute vertical out rows t' -> t; fp32 out + bf16 mirror ----
__global__ __launch_bounds__(512)
void permute_va(const float* __restrict__ VOX, float* __restrict__ vax,
                unsigned short* __restrict__ vaxb) {
    const int t = blockIdx.x;          // t = p*8+b
    const int c = threadIdx.x;
    const int p = t >> 3, b = t & 7;
    const int hh = p >> 6, ww = p & 63;
    const int nw = ww >> 2, wd = ww & 3;
    const int tp = ((hh << 2) + wd) * 128 + (b << 4) + nw;
    float v = VOX[(size_t)tp * CD + c];
    vax[(size_t)t * CD + c]  = v;
    vaxb[(size_t)t * CD + c] = f2bf(v);
}

// ------ concat [HA|VA] -> attn_bchw + partial sums of res = attn + x ------
__global__ __launch_bounds__(256)
void concat_stats(const float* __restrict__ HA, const float* __restrict__ VA,
                  const float* __restrict__ x, float* __restrict__ attn_out,
                  float* __restrict__ stats) {
    __shared__ float tile[32][33];
    const int b  = blockIdx.z;
    const int p0 = blockIdx.x << 5;
    const int c0 = blockIdx.y << 5;
    const int tx = threadIdx.x;   // 32
    const int ty = threadIdx.y;   // 8
#pragma unroll
    for (int i = 0; i < 4; i++) {
        int c = c0 + tx;
        int p = p0 + ty + (i << 3);
        size_t t = (size_t)p * BB + b;
        float v = (c < C1D) ? HA[t * C1D + c] : VA[t * C2D + (c - C1D)];
        tile[ty + (i << 3)][tx] = v;
    }
    __syncthreads();
    float lsum = 0.f, lsq = 0.f;
#pragma unroll
    for (int i = 0; i < 4; i++) {
        int c = c0 + ty + (i << 3);
        int p = p0 + tx;
        size_t o = ((size_t)b * CD + c) * PP + p;
        float v = tile[tx][ty + (i << 3)];
        attn_out[o] = v;
        float r = v + x[o];
        lsum += r; lsq += r * r;
    }
    for (int off = 32; off; off >>= 1) {
        lsum += __shfl_xor(lsum, off);
        lsq  += __shfl_xor(lsq, off);
    }
    __shared__ float wsum[4], wsq[4];
    const int tl = ty * 32 + tx;
    if ((tl & 63) == 0) { wsum[tl >> 6] = lsum; wsq[tl >> 6] = lsq; }
    __syncthreads();
    if (tl == 0) {
        atomicAdd(&stats[b],     wsum[0] + wsum[1] + wsum[2] + wsum[3]);
        atomicAdd(&stats[8 + b], wsq[0] + wsq[1] + wsq[2] + wsq[3]);
    }
}

__global__ void stats_final(float* stats) {
    int b = threadIdx.x;
    if (b < 8) {
        const float n = (float)CD * (float)PP;
        float mu  = stats[b] / n;
        float var = stats[8 + b] / n - mu * mu;
        stats[16 + b] = mu;
        stats[24 + b] = 1.f / sqrtf(var + 1e-5f);
    }
}

__global__ __launch_bounds__(256)
void norm_kernel(const float* __restrict__ attn, const float* __restrict__ x,
                 const float* __restrict__ stats, float* __restrict__ out) {
    size_t i = ((size_t)blockIdx.x * blockDim.x + threadIdx.x) * 4;
    int b = (int)(i >> 21);
    float mu  = stats[16 + b];
    float inv = stats[24 + b];
    const float4 a4 = *reinterpret_cast<const float4*>(attn + i);
    const float4 x4 = *reinterpret_cast<const float4*>(x + i);
    float4 r;
    r.x = (a4.x + x4.x - mu) * inv;
    r.y = (a4.y + x4.y - mu) * inv;
    r.z = (a4.z + x4.z - mu) * inv;
    r.w = (a4.w + x4.w - mu) * inv;
    *reinterpret_cast<float4*>(out + i) = r;
}

// ---------------- host launch ----------------
extern "C" void kernel_launch(void* const* d_in, const int* in_sizes, int n_in,
                              void* d_out, int out_size, void* d_ws, size_t ws_size,
                              hipStream_t stream) {
    const float* x     = (const float*)d_in[0];
    const float* hinw  = (const float*)d_in[1];
    const float* hinb  = (const float*)d_in[2];
    const float* houtw = (const float*)d_in[3];
    const float* houtb = (const float*)d_in[4];
    const float* vinw  = (const float*)d_in[5];
    const float* vinb  = (const float*)d_in[6];
    const float* voutw = (const float*)d_in[7];
    const float* voutb = (const float*)d_in[8];
    const float* hfcw  = (const float*)d_in[9];
    const float* hfcb  = (const float*)d_in[10];
    const float* vfcw  = (const float*)d_in[11];
    const float* vfcb  = (const float*)d_in[12];

    char* wsb = (char*)d_ws;
    unsigned short* R0  = (unsigned short*)(wsb);               // XT -> HAXB -> KVb
    unsigned short* R1  = (unsigned short*)(wsb + 33554432);    // Q/O both branches
    unsigned short* R2  = (unsigned short*)(wsb + 67108864);    // XV -> VAXB
    unsigned short* R3  = (unsigned short*)(wsb + 100663296);   // VVb
    unsigned short* XP  = (unsigned short*)(wsb + 134217728);
    unsigned short* KHb = (unsigned short*)(wsb + 136314880);
    unsigned short* VHb = (unsigned short*)(wsb + 138412032);
    float* HA = (float*)(wsb + 140509184);                       // [32768][358]
    float* VA = (float*)(wsb + 187432960);                       // [32768][154]
    unsigned short* Whin  = (unsigned short*)(wsb + 207618048);  // [1536][512]
    unsigned short* Whout = Whin + 786432;                       // [512][512]
    unsigned short* Wvin  = Whout + 262144;                      // [1536][512]
    unsigned short* Wvout = Wvin + 786432;                       // [512][512]
    unsigned short* Whfc  = Wvout + 262144;                      // [384][512] padded
    unsigned short* Wvfc  = Whfc + 196608;                       // [256][512] padded
    float* STATS = (float*)(wsb + 212467712);

    float* out_res = (float*)d_out;
    float* out_hax = out_res + 16777216;
    float* out_vax = out_res + 33554432;
    float* out_att = out_res + 50331648;   // also VOX fp32 scratch (t' order)

    hipMemsetAsync(STATS, 0, 32 * sizeof(float), stream);

    // weights -> bf16 (+ padded FC weights)
    cast_w<<<3072, 256, 0, stream>>>(hinw,  Whin,  786432);
    cast_w<<<1024, 256, 0, stream>>>(houtw, Whout, 262144);
    cast_w<<<3072, 256, 0, stream>>>(vinw,  Wvin,  786432);
    cast_w<<<1024, 256, 0, stream>>>(voutw, Wvout, 262144);
    pad_w<<<768, 256, 0, stream>>>(hfcw, Whfc, C1D, 384, CD);
    pad_w<<<512, 256, 0, stream>>>(vfcw, Wvfc, C2D, 256, CD);

    const dim3 tb(32, 8, 1);
    const dim3 tgrid(128, 16, 8);

    // ---- horizontal branch ----
    transpose_x<<<tgrid, tb, 0, stream>>>(x, R0);                                    // XT
    pool_from_xt<<<2048, 512, 0, stream>>>(R0, XP);
    gemm_mfma<<<dim3(4, 256), 256, 0, stream>>>(R0, Whin, hinb, nullptr, R1, NT, CD, CD);            // QH
    gemm_mfma<<<dim3(4, 16), 256, 0, stream>>>(XP, Whin + 262144, hinb + CD, nullptr, KHb, 2048, CD, CD);   // KH
    gemm_mfma<<<dim3(4, 16), 256, 0, stream>>>(XP, Whin + 524288, hinb + 2 * CD, nullptr, VHb, 2048, CD, CD); // VH
    attn_mfma<<<dim3(32, 64), 512, 0, stream>>>(R1, KHb, VHb, R1, BB, 1, 1, 256);    // OH in-place
    gemm_mfma<<<dim3(4, 256), 256, 0, stream>>>(R1, Whout, houtb, out_hax, R0, NT, CD, CD);          // ha_x (+bf16)
    gemm_mfma<<<dim3(3, 256), 256, 0, stream>>>(R0, Whfc, hfcb, HA, nullptr, NT, CD, C1D);           // HA

    // ---- vertical branch ----
    make_xv<<<tgrid, tb, 0, stream>>>(x, R2);                                        // XV
    gemm_mfma<<<dim3(4, 256), 256, 0, stream>>>(R2, Wvin, vinb, nullptr, R1, NT, CD, CD);            // QV
    gemm_mfma<<<dim3(4, 256), 256, 0, stream>>>(R2, Wvin + 262144, vinb + CD, nullptr, R0, NT, CD, CD);     // KV
    gemm_mfma<<<dim3(4, 256), 256, 0, stream>>>(R2, Wvin + 524288, vinb + 2 * CD, nullptr, R3, NT, CD, CD); // VV
    attn_mfma<<<dim3(2, 1024), 512, 0, stream>>>(R1, R0, R3, R1, 128, 1, 128, 1);    // OV in-place
    gemm_mfma<<<dim3(4, 256), 256, 0, stream>>>(R1, Wvout, voutb, out_att, nullptr, NT, CD, CD);     // VOX fp32
    permute_va<<<NT, 512, 0, stream>>>(out_att, out_vax, R2);                        // va_x + bf16
    gemm_mfma<<<dim3(2, 256), 256, 0, stream>>>(R2, Wvfc, vfcb, VA, nullptr, NT, CD, C2D);           // VA

    // ---- concat + residual + layernorm ----
    concat_stats<<<tgrid, tb, 0, stream>>>(HA, VA, x, out_att, STATS);
    stats_final<<<1, 8, 0, stream>>>(STATS);
    norm_kernel<<<16384, 256, 0, stream>>>(out_att, x, STATS, out_res);
}

// Round 5
// 958.848 us; speedup vs baseline: 6.2152x; 1.3908x over previous
//
#include <hip/hip_runtime.h>
#include <cstdint>
#include <cstddef>

// ---------------- problem constants ----------------
#define CD    512
#define HD    64
#define C1D   358
#define C2D   154
#define BB    8
#define PP    4096
#define NT    32768
#define LKK   256

typedef __attribute__((ext_vector_type(8))) short bf16x8;
typedef __attribute__((ext_vector_type(4))) float f32x4;

__device__ __forceinline__ unsigned short f2bf(float f) {
    union { float f; unsigned u; } v; v.f = f;
    unsigned r = v.u + 0x7FFF + ((v.u >> 16) & 1);
    return (unsigned short)(r >> 16);
}
__device__ __forceinline__ float bf2f(unsigned short s) {
    union { unsigned u; float f; } v; v.u = ((unsigned)s) << 16;
    return v.f;
}

#define GL_LDS16(gp, lp) __builtin_amdgcn_global_load_lds( \
    (const __attribute__((address_space(1))) unsigned int*)(gp), \
    (__attribute__((address_space(3))) unsigned int*)(lp), 16, 0, 0)

// ---------------- weight casts ----------------
__global__ __launch_bounds__(256)
void cast_w(const float* __restrict__ src, unsigned short* __restrict__ dst, int n) {
    int i = blockIdx.x * 256 + threadIdx.x;
    if (i < n) dst[i] = f2bf(src[i]);
}

// pad [Nreal][K] -> [Npad][K], zero-filled rows >= Nreal
__global__ __launch_bounds__(256)
void pad_w(const float* __restrict__ src, unsigned short* __restrict__ dst,
           int Nreal, int Npad, int K) {
    int i = blockIdx.x * 256 + threadIdx.x;
    if (i < Npad * K) {
        int r = i / K, c = i - r * K;
        dst[i] = (r < Nreal) ? f2bf(src[(size_t)r * K + c]) : 0;
    }
}

// -------- transpose x (b,c,p) -> Xt[(p*8+b)*512+c] (bf16) --------
__global__ __launch_bounds__(256)
void transpose_x(const float* __restrict__ x, unsigned short* __restrict__ Xt) {
    __shared__ float tile[32][33];
    const int b  = blockIdx.z;
    const int p0 = blockIdx.x << 5;
    const int c0 = blockIdx.y << 5;
    const int tx = threadIdx.x;   // 32
    const int ty = threadIdx.y;   // 8
#pragma unroll
    for (int i = 0; i < 4; i++) {
        int c = c0 + ty + (i << 3);
        tile[ty + (i << 3)][tx] = x[((size_t)b * CD + c) * PP + p0 + tx];
    }
    __syncthreads();
#pragma unroll
    for (int i = 0; i < 4; i++) {
        int p = p0 + ty + (i << 3);
        Xt[((size_t)p * BB + b) * CD + c0 + tx] = f2bf(tile[tx][ty + (i << 3)]);
    }
}

// ---- x (b,c,p) -> Xv[t'*512+c] bf16, t' = (hh*4+wd)*128 + b*16 + nw ----
__global__ __launch_bounds__(256)
void make_xv(const float* __restrict__ x, unsigned short* __restrict__ Xv) {
    __shared__ float tile[32][33];
    const int b  = blockIdx.z;
    const int p0 = blockIdx.x << 5;
    const int c0 = blockIdx.y << 5;
    const int tx = threadIdx.x;
    const int ty = threadIdx.y;
#pragma unroll
    for (int i = 0; i < 4; i++) {
        int c = c0 + ty + (i << 3);
        tile[ty + (i << 3)][tx] = x[((size_t)b * CD + c) * PP + p0 + tx];
    }
    __syncthreads();
#pragma unroll
    for (int i = 0; i < 4; i++) {
        int p  = p0 + ty + (i << 3);
        int c  = c0 + tx;
        int hh = p >> 6, ww = p & 63;
        int nw = ww >> 2, wd = ww & 3;
        int tp = ((hh << 2) + wd) * 128 + (b << 4) + nw;
        Xv[(size_t)tp * CD + c] = f2bf(tile[tx][ty + (i << 3)]);
    }
}

// ---- pool: Xp[(b*256+k)*512+c] = mean of 4x4 window (bf16 in/out) ----
__global__ __launch_bounds__(512)
void pool_from_xt(const unsigned short* __restrict__ Xt, unsigned short* __restrict__ Xp) {
    const int u = blockIdx.x;          // b*256+k
    const int c = threadIdx.x;         // 512
    const int b = u >> 8, k = u & 255;
    const int ph = k >> 4, pw = k & 15;
    float s = 0.f;
#pragma unroll
    for (int dy = 0; dy < 4; dy++)
#pragma unroll
        for (int dx = 0; dx < 4; dx++) {
            int p = ((ph << 2) + dy) * 64 + (pw << 2) + dx;
            s += bf2f(Xt[((size_t)p * BB + b) * CD + c]);
        }
    Xp[(size_t)u * CD + c] = f2bf(s * (1.f / 16.f));
}

// ---------------- MFMA GEMM ----------------
// C[m][n] = sum_k A[m][k]*W[n][k] + bias[n]; A [M][K] bf16, W [Npad][K] bf16.
// 128x128 tile, BK=64, 256 threads (4 waves 2x2), double-buffered LDS,
// global_load_lds width-16 staging. Optional fp32 and bf16 outputs.
__device__ __forceinline__ void stage_tile(const unsigned short* __restrict__ g,
                                           unsigned short* l, int K, int tid) {
#pragma unroll
    for (int i = 0; i < 4; i++) {
        int c  = i * 256 + tid;           // 16B chunk id, 0..1023
        int r  = c >> 3;                  // row 0..127
        int ko = (c & 7) << 3;            // k offset 0..56
        GL_LDS16(g + (size_t)r * K + ko, l + c * 8);
    }
}

__global__ __launch_bounds__(256)
void gemm_mfma(const unsigned short* __restrict__ A, const unsigned short* __restrict__ W,
               const float* __restrict__ bias,
               float* __restrict__ Cf, unsigned short* __restrict__ Cb,
               int M, int K, int Nreal) {
    __shared__ unsigned short ldsA[2][128][64];
    __shared__ unsigned short ldsB[2][128][64];
    const int tid  = threadIdx.x;
    const int lane = tid & 63;
    const int wid  = tid >> 6;
    const int wr = wid >> 1, wc = wid & 1;
    const int lr = lane & 15, lg = lane >> 4;
    const int row0 = blockIdx.y << 7;
    const int col0 = blockIdx.x << 7;

    f32x4 zero = {0.f, 0.f, 0.f, 0.f};
    f32x4 acc[4][4];
#pragma unroll
    for (int m = 0; m < 4; m++)
#pragma unroll
        for (int n = 0; n < 4; n++) acc[m][n] = zero;

    const unsigned short* Ab = A + (size_t)row0 * K;
    const unsigned short* Wb = W + (size_t)col0 * K;

    stage_tile(Ab, &ldsA[0][0][0], K, tid);
    stage_tile(Wb, &ldsB[0][0][0], K, tid);
    __syncthreads();

    const int NTILES = K >> 6;
    int buf = 0;
    for (int t = 0; t < NTILES; t++) {
        if (t + 1 < NTILES) {
            stage_tile(Ab + ((t + 1) << 6), &ldsA[buf ^ 1][0][0], K, tid);
            stage_tile(Wb + ((t + 1) << 6), &ldsB[buf ^ 1][0][0], K, tid);
        }
#pragma unroll
        for (int kk = 0; kk < 2; kk++) {
            bf16x8 af[4], bfr[4];
#pragma unroll
            for (int m = 0; m < 4; m++)
                af[m] = *reinterpret_cast<const bf16x8*>(&ldsA[buf][wr * 64 + m * 16 + lr][kk * 32 + lg * 8]);
#pragma unroll
            for (int n = 0; n < 4; n++)
                bfr[n] = *reinterpret_cast<const bf16x8*>(&ldsB[buf][wc * 64 + n * 16 + lr][kk * 32 + lg * 8]);
#pragma unroll
            for (int m = 0; m < 4; m++)
#pragma unroll
                for (int n = 0; n < 4; n++)
                    acc[m][n] = __builtin_amdgcn_mfma_f32_16x16x32_bf16(af[m], bfr[n], acc[m][n], 0, 0, 0);
        }
        __syncthreads();
        buf ^= 1;
    }

    // epilogue
#pragma unroll
    for (int n = 0; n < 4; n++) {
        int col = col0 + wc * 64 + n * 16 + lr;
        bool cok = col < Nreal;
        float bv = cok ? bias[col] : 0.f;
#pragma unroll
        for (int m = 0; m < 4; m++) {
            int row = row0 + wr * 64 + m * 16 + lg * 4;
            if (cok) {
#pragma unroll
                for (int i = 0; i < 4; i++) {
                    float v = acc[m][n][i] + bv;
                    if (Cf) Cf[(size_t)(row + i) * Nreal + col] = v;
                    if (Cb) Cb[(size_t)(row + i) * Nreal + col] = f2bf(v);
                }
            }
        }
    }
}

// ---------------- MFMA fused attention (Lk=256, D=64) ----------------
// token row address = q*QT + bi*QB (Q/O), k*KT + bi*KB (K/V); all bf16 [*][512]
// block: 512 threads = 8 waves; each wave owns 16 q-rows. O may alias Q.
__global__ __launch_bounds__(512)
void attn_mfma(const unsigned short* __restrict__ Q, const unsigned short* __restrict__ Kp,
               const unsigned short* __restrict__ Vp, unsigned short* __restrict__ O,
               int QT, int QB, int KT, int KB) {
    __shared__ unsigned short Kb[256][72];    // [k][d], +8 pad
    __shared__ unsigned short Vt[64][264];    // [d][k], +8 pad
    __shared__ unsigned short Pl[8][16][264]; // per-wave P tile
    const int tid  = threadIdx.x;
    const int lane = tid & 63;
    const int w    = tid >> 6;
    const int lr = lane & 15, lg = lane >> 4;
    const int bh = blockIdx.y, bi = bh >> 3, h = bh & 7;
    const int q0 = blockIdx.x << 7;

    // stage K and V^T
    for (int idx = tid; idx < 8192; idx += 512) {
        int k  = idx >> 5;
        int d2 = (idx & 31) << 1;
        size_t grow = ((size_t)k * KT + (size_t)bi * KB) * CD + h * HD + d2;
        unsigned int kv = *reinterpret_cast<const unsigned int*>(&Kp[grow]);
        unsigned int vv = *reinterpret_cast<const unsigned int*>(&Vp[grow]);
        Kb[k][d2]     = (unsigned short)(kv & 0xffff);
        Kb[k][d2 + 1] = (unsigned short)(kv >> 16);
        Vt[d2][k]     = (unsigned short)(vv & 0xffff);
        Vt[d2 + 1][k] = (unsigned short)(vv >> 16);
    }
    __syncthreads();

    // Q fragments (held in regs; enables in-place O)
    const int qrow = q0 + w * 16 + lr;
    const size_t qbase = ((size_t)qrow * QT + (size_t)bi * QB) * CD + h * HD;
    bf16x8 qf0 = *reinterpret_cast<const bf16x8*>(&Q[qbase + lg * 8]);
    bf16x8 qf1 = *reinterpret_cast<const bf16x8*>(&Q[qbase + 32 + lg * 8]);

    // S = Q K^T  (16 col-tiles of 16)
    f32x4 zero = {0.f, 0.f, 0.f, 0.f};
    f32x4 sacc[16];
#pragma unroll
    for (int t = 0; t < 16; t++) sacc[t] = zero;
#pragma unroll
    for (int t = 0; t < 16; t++) {
        bf16x8 kb0 = *reinterpret_cast<const bf16x8*>(&Kb[t * 16 + lr][lg * 8]);
        bf16x8 kb1 = *reinterpret_cast<const bf16x8*>(&Kb[t * 16 + lr][32 + lg * 8]);
        sacc[t] = __builtin_amdgcn_mfma_f32_16x16x32_bf16(qf0, kb0, sacc[t], 0, 0, 0);
        sacc[t] = __builtin_amdgcn_mfma_f32_16x16x32_bf16(qf1, kb1, sacc[t], 0, 0, 0);
    }
#pragma unroll
    for (int t = 0; t < 16; t++) sacc[t] = sacc[t] * 0.125f;

    // softmax over 256 cols; lane holds rows lg*4+i, cols t*16+lr
    float mrow[4] = {-1e30f, -1e30f, -1e30f, -1e30f};
#pragma unroll
    for (int t = 0; t < 16; t++)
#pragma unroll
        for (int i = 0; i < 4; i++) mrow[i] = fmaxf(mrow[i], sacc[t][i]);
#pragma unroll
    for (int i = 0; i < 4; i++) {
        mrow[i] = fmaxf(mrow[i], __shfl_xor(mrow[i], 1));
        mrow[i] = fmaxf(mrow[i], __shfl_xor(mrow[i], 2));
        mrow[i] = fmaxf(mrow[i], __shfl_xor(mrow[i], 4));
        mrow[i] = fmaxf(mrow[i], __shfl_xor(mrow[i], 8));
    }
    float ssum[4] = {0.f, 0.f, 0.f, 0.f};
#pragma unroll
    for (int t = 0; t < 16; t++)
#pragma unroll
        for (int i = 0; i < 4; i++) {
            float p = __expf(sacc[t][i] - mrow[i]);
            sacc[t][i] = p;
            ssum[i] += p;
        }
#pragma unroll
    for (int i = 0; i < 4; i++) {
        ssum[i] += __shfl_xor(ssum[i], 1);
        ssum[i] += __shfl_xor(ssum[i], 2);
        ssum[i] += __shfl_xor(ssum[i], 4);
        ssum[i] += __shfl_xor(ssum[i], 8);
    }
    float rinv[4];
#pragma unroll
    for (int i = 0; i < 4; i++) rinv[i] = 1.f / ssum[i];

    // write P (bf16) to this wave's LDS tile
#pragma unroll
    for (int t = 0; t < 16; t++)
#pragma unroll
        for (int i = 0; i < 4; i++)
            Pl[w][lg * 4 + i][t * 16 + lr] = f2bf(sacc[t][i] * rinv[i]);

    // O = P V  (4 d-tiles of 16, 8 k-steps of 32)
    f32x4 oacc[4];
#pragma unroll
    for (int n = 0; n < 4; n++) oacc[n] = zero;
#pragma unroll
    for (int ks = 0; ks < 8; ks++) {
        bf16x8 pa = *reinterpret_cast<const bf16x8*>(&Pl[w][lr][ks * 32 + lg * 8]);
#pragma unroll
        for (int n = 0; n < 4; n++) {
            bf16x8 vb = *reinterpret_cast<const bf16x8*>(&Vt[n * 16 + lr][ks * 32 + lg * 8]);
            oacc[n] = __builtin_amdgcn_mfma_f32_16x16x32_bf16(pa, vb, oacc[n], 0, 0, 0);
        }
    }
#pragma unroll
    for (int n = 0; n < 4; n++)
#pragma unroll
        for (int i = 0; i < 4; i++) {
            int qr2 = q0 + w * 16 + lg * 4 + i;
            size_t ob = ((size_t)qr2 * QT + (size_t)bi * QB) * CD + h * HD + n * 16 + lr;
            O[ob] = f2bf(oacc[n][i]);
        }
}

// ---- permute vertical out rows t' -> t; fp32 out + bf16 mirror ----
__global__ __launch_bounds__(512)
void permute_va(const float* __restrict__ VOX, float* __restrict__ vax,
                unsigned short* __restrict__ vaxb) {
    const int t = blockIdx.x;          // t = p*8+b
    const int c = threadIdx.x;
    const int p = t >> 3, b = t & 7;
    const int hh = p >> 6, ww = p & 63;
    const int nw = ww >> 2, wd = ww & 3;
    const int tp = ((hh << 2) + wd) * 128 + (b << 4) + nw;
    float v = VOX[(size_t)tp * CD + c];
    vax[(size_t)t * CD + c]  = v;
    vaxb[(size_t)t * CD + c] = f2bf(v);
}

// ------ concat [HA|VA] -> attn_bchw + per-block partial sums (NO atomics) ------
// grid (32,16,8), block 32x8. Each block: 128 p x 32 c tile (4 sub-tiles).
__global__ __launch_bounds__(256)
void concat_stats(const float* __restrict__ HA, const float* __restrict__ VA,
                  const float* __restrict__ x, float* __restrict__ attn_out,
                  float* __restrict__ PS, float* __restrict__ PQ) {
    __shared__ float tile[32][33];
    __shared__ float wsum[4], wsq[4];
    const int b  = blockIdx.z;
    const int c0 = blockIdx.y << 5;
    const int tx = threadIdx.x;   // 32
    const int ty = threadIdx.y;   // 8
    const int tl = ty * 32 + tx;
    float lsum = 0.f, lsq = 0.f;

    for (int s = 0; s < 4; s++) {
        const int p0 = ((blockIdx.x << 2) + s) << 5;
#pragma unroll
        for (int i = 0; i < 4; i++) {
            int c = c0 + tx;
            int p = p0 + ty + (i << 3);
            size_t t = (size_t)p * BB + b;
            float v = (c < C1D) ? HA[t * C1D + c] : VA[t * C2D + (c - C1D)];
            tile[ty + (i << 3)][tx] = v;
        }
        __syncthreads();
#pragma unroll
        for (int i = 0; i < 4; i++) {
            int c = c0 + ty + (i << 3);
            int p = p0 + tx;
            size_t o = ((size_t)b * CD + c) * PP + p;
            float v = tile[tx][ty + (i << 3)];
            attn_out[o] = v;
            float r = v + x[o];
            lsum += r; lsq += r * r;
        }
        __syncthreads();
    }

    for (int off = 32; off; off >>= 1) {
        lsum += __shfl_xor(lsum, off);
        lsq  += __shfl_xor(lsq, off);
    }
    if ((tl & 63) == 0) { wsum[tl >> 6] = lsum; wsq[tl >> 6] = lsq; }
    __syncthreads();
    if (tl == 0) {
        const int bid = blockIdx.z * 512 + blockIdx.y * 32 + blockIdx.x;
        PS[bid] = wsum[0] + wsum[1] + wsum[2] + wsum[3];
        PQ[bid] = wsq[0] + wsq[1] + wsq[2] + wsq[3];
    }
}

// ---- final reduce: wave b sums its 512 partials -> mu, inv-std ----
__global__ __launch_bounds__(512)
void stats_final2(const float* __restrict__ PS, const float* __restrict__ PQ,
                  float* __restrict__ stats) {
    const int w    = threadIdx.x >> 6;   // 8 waves -> batch index
    const int lane = threadIdx.x & 63;
    float s = 0.f, q = 0.f;
    for (int i = lane; i < 512; i += 64) {
        s += PS[w * 512 + i];
        q += PQ[w * 512 + i];
    }
    for (int off = 32; off; off >>= 1) {
        s += __shfl_xor(s, off);
        q += __shfl_xor(q, off);
    }
    if (lane == 0) {
        const float n = (float)CD * (float)PP;
        float mu  = s / n;
        float var = q / n - mu * mu;
        stats[16 + w] = mu;
        stats[24 + w] = 1.f / sqrtf(var + 1e-5f);
    }
}

__global__ __launch_bounds__(256)
void norm_kernel(const float* __restrict__ attn, const float* __restrict__ x,
                 const float* __restrict__ stats, float* __restrict__ out) {
    size_t i = ((size_t)blockIdx.x * blockDim.x + threadIdx.x) * 4;
    int b = (int)(i >> 21);
    float mu  = stats[16 + b];
    float inv = stats[24 + b];
    const float4 a4 = *reinterpret_cast<const float4*>(attn + i);
    const float4 x4 = *reinterpret_cast<const float4*>(x + i);
    float4 r;
    r.x = (a4.x + x4.x - mu) * inv;
    r.y = (a4.y + x4.y - mu) * inv;
    r.z = (a4.z + x4.z - mu) * inv;
    r.w = (a4.w + x4.w - mu) * inv;
    *reinterpret_cast<float4*>(out + i) = r;
}

// ---------------- host launch ----------------
extern "C" void kernel_launch(void* const* d_in, const int* in_sizes, int n_in,
                              void* d_out, int out_size, void* d_ws, size_t ws_size,
                              hipStream_t stream) {
    const float* x     = (const float*)d_in[0];
    const float* hinw  = (const float*)d_in[1];
    const float* hinb  = (const float*)d_in[2];
    const float* houtw = (const float*)d_in[3];
    const float* houtb = (const float*)d_in[4];
    const float* vinw  = (const float*)d_in[5];
    const float* vinb  = (const float*)d_in[6];
    const float* voutw = (const float*)d_in[7];
    const float* voutb = (const float*)d_in[8];
    const float* hfcw  = (const float*)d_in[9];
    const float* hfcb  = (const float*)d_in[10];
    const float* vfcw  = (const float*)d_in[11];
    const float* vfcb  = (const float*)d_in[12];

    char* wsb = (char*)d_ws;
    unsigned short* R0  = (unsigned short*)(wsb);               // XT -> HAXB -> KVb
    unsigned short* R1  = (unsigned short*)(wsb + 33554432);    // Q/O both branches
    unsigned short* R2  = (unsigned short*)(wsb + 67108864);    // XV -> VAXB
    unsigned short* R3  = (unsigned short*)(wsb + 100663296);   // VVb
    unsigned short* XP  = (unsigned short*)(wsb + 134217728);
    unsigned short* KHb = (unsigned short*)(wsb + 136314880);
    unsigned short* VHb = (unsigned short*)(wsb + 138412032);
    float* HA = (float*)(wsb + 140509184);                       // [32768][358]
    float* VA = (float*)(wsb + 187432960);                       // [32768][154]
    unsigned short* Whin  = (unsigned short*)(wsb + 207618048);  // [1536][512]
    unsigned short* Whout = Whin + 786432;                       // [512][512]
    unsigned short* Wvin  = Whout + 262144;                      // [1536][512]
    unsigned short* Wvout = Wvin + 786432;                       // [512][512]
    unsigned short* Whfc  = Wvout + 262144;                      // [384][512] padded
    unsigned short* Wvfc  = Whfc + 196608;                       // [256][512] padded
    float* STATS = (float*)(wsb + 212467712);                    // 32 floats
    float* PS    = (float*)(wsb + 212471808);                    // 4096 floats
    float* PQ    = PS + 4096;                                    // 4096 floats

    float* out_res = (float*)d_out;
    float* out_hax = out_res + 16777216;
    float* out_vax = out_res + 33554432;
    float* out_att = out_res + 50331648;   // also VOX fp32 scratch (t' order)

    // weights -> bf16 (+ padded FC weights)
    cast_w<<<3072, 256, 0, stream>>>(hinw,  Whin,  786432);
    cast_w<<<1024, 256, 0, stream>>>(houtw, Whout, 262144);
    cast_w<<<3072, 256, 0, stream>>>(vinw,  Wvin,  786432);
    cast_w<<<1024, 256, 0, stream>>>(voutw, Wvout, 262144);
    pad_w<<<768, 256, 0, stream>>>(hfcw, Whfc, C1D, 384, CD);
    pad_w<<<512, 256, 0, stream>>>(vfcw, Wvfc, C2D, 256, CD);

    const dim3 tb(32, 8, 1);
    const dim3 tgrid(128, 16, 8);

    // ---- horizontal branch ----
    transpose_x<<<tgrid, tb, 0, stream>>>(x, R0);                                    // XT
    pool_from_xt<<<2048, 512, 0, stream>>>(R0, XP);
    gemm_mfma<<<dim3(4, 256), 256, 0, stream>>>(R0, Whin, hinb, nullptr, R1, NT, CD, CD);            // QH
    gemm_mfma<<<dim3(4, 16), 256, 0, stream>>>(XP, Whin + 262144, hinb + CD, nullptr, KHb, 2048, CD, CD);   // KH
    gemm_mfma<<<dim3(4, 16), 256, 0, stream>>>(XP, Whin + 524288, hinb + 2 * CD, nullptr, VHb, 2048, CD, CD); // VH
    attn_mfma<<<dim3(32, 64), 512, 0, stream>>>(R1, KHb, VHb, R1, BB, 1, 1, 256);    // OH in-place
    gemm_mfma<<<dim3(4, 256), 256, 0, stream>>>(R1, Whout, houtb, out_hax, R0, NT, CD, CD);          // ha_x (+bf16)
    gemm_mfma<<<dim3(3, 256), 256, 0, stream>>>(R0, Whfc, hfcb, HA, nullptr, NT, CD, C1D);           // HA

    // ---- vertical branch ----
    make_xv<<<tgrid, tb, 0, stream>>>(x, R2);                                        // XV
    gemm_mfma<<<dim3(4, 256), 256, 0, stream>>>(R2, Wvin, vinb, nullptr, R1, NT, CD, CD);            // QV
    gemm_mfma<<<dim3(4, 256), 256, 0, stream>>>(R2, Wvin + 262144, vinb + CD, nullptr, R0, NT, CD, CD);     // KV
    gemm_mfma<<<dim3(4, 256), 256, 0, stream>>>(R2, Wvin + 524288, vinb + 2 * CD, nullptr, R3, NT, CD, CD); // VV
    attn_mfma<<<dim3(2, 1024), 512, 0, stream>>>(R1, R0, R3, R1, 128, 1, 128, 1);    // OV in-place
    gemm_mfma<<<dim3(4, 256), 256, 0, stream>>>(R1, Wvout, voutb, out_att, nullptr, NT, CD, CD);     // VOX fp32
    permute_va<<<NT, 512, 0, stream>>>(out_att, out_vax, R2);                        // va_x + bf16
    gemm_mfma<<<dim3(2, 256), 256, 0, stream>>>(R2, Wvfc, vfcb, VA, nullptr, NT, CD, C2D);           // VA

    // ---- concat + residual + layernorm (two-stage reduction, no atomics) ----
    concat_stats<<<dim3(32, 16, 8), tb, 0, stream>>>(HA, VA, x, out_att, PS, PQ);
    stats_final2<<<1, 512, 0, stream>>>(PS, PQ, STATS);
    norm_kernel<<<16384, 256, 0, stream>>>(out_att, x, STATS, out_res);
}

// Round 7
// 846.076 us; speedup vs baseline: 7.0437x; 1.1333x over previous
//
#include <hip/hip_runtime.h>
#include <cstdint>
#include <cstddef>

// ---------------- problem constants ----------------
#define CD    512
#define HD    64
#define C1D   358
#define C2D   154
#define BB    8
#define PP    4096
#define NT    32768
#define LKK   256

typedef __attribute__((ext_vector_type(8))) short bf16x8;
typedef __attribute__((ext_vector_type(4))) float f32x4;

__device__ __forceinline__ unsigned short f2bf(float f) {
    union { float f; unsigned u; } v; v.f = f;
    unsigned r = v.u + 0x7FFF + ((v.u >> 16) & 1);
    return (unsigned short)(r >> 16);
}
__device__ __forceinline__ float bf2f(unsigned short s) {
    union { unsigned u; float f; } v; v.u = ((unsigned)s) << 16;
    return v.f;
}

#define GL_LDS16(gp, lp) __builtin_amdgcn_global_load_lds( \
    (const __attribute__((address_space(1))) unsigned int*)(gp), \
    (__attribute__((address_space(3))) unsigned int*)(lp), 16, 0, 0)

// -------- all weight casts + pads in ONE dispatch (2,424,832 threads exact) --------
__global__ __launch_bounds__(256)
void cast_all(const float* __restrict__ hinw, const float* __restrict__ houtw,
              const float* __restrict__ vinw, const float* __restrict__ voutw,
              const float* __restrict__ hfcw, const float* __restrict__ vfcw,
              unsigned short* __restrict__ Whin, unsigned short* __restrict__ Whout,
              unsigned short* __restrict__ Wvin, unsigned short* __restrict__ Wvout,
              unsigned short* __restrict__ Whfc, unsigned short* __restrict__ Wvfc) {
    int i = blockIdx.x * 256 + threadIdx.x;
    if (i < 786432) { Whin[i] = f2bf(hinw[i]); return; }
    i -= 786432;
    if (i < 262144) { Whout[i] = f2bf(houtw[i]); return; }
    i -= 262144;
    if (i < 786432) { Wvin[i] = f2bf(vinw[i]); return; }
    i -= 786432;
    if (i < 262144) { Wvout[i] = f2bf(voutw[i]); return; }
    i -= 262144;
    if (i < 196608) {   // hfc pad [384][512], Nreal=358
        int r = i >> 9, c = i & 511;
        Whfc[i] = (r < C1D) ? f2bf(hfcw[r * CD + c]) : 0;
        return;
    }
    i -= 196608;
    {                   // vfc pad [256][512], Nreal=154
        int r = i >> 9, c = i & 511;
        Wvfc[i] = (r < C2D) ? f2bf(vfcw[r * CD + c]) : 0;
    }
}

// -------- one pass over x -> Xt[(p*8+b)*512+c] AND Xv[t'*512+c] (bf16) --------
__global__ __launch_bounds__(256)
void transpose_both(const float* __restrict__ x, unsigned short* __restrict__ Xt,
                    unsigned short* __restrict__ Xv) {
    __shared__ float tile[32][33];
    const int b  = blockIdx.z;
    const int p0 = blockIdx.x << 5;
    const int c0 = blockIdx.y << 5;
    const int tx = threadIdx.x;   // 32
    const int ty = threadIdx.y;   // 8
#pragma unroll
    for (int i = 0; i < 4; i++) {
        int c = c0 + ty + (i << 3);
        tile[ty + (i << 3)][tx] = x[((size_t)b * CD + c) * PP + p0 + tx];
    }
    __syncthreads();
#pragma unroll
    for (int i = 0; i < 4; i++) {
        int p  = p0 + ty + (i << 3);
        int c  = c0 + tx;
        unsigned short v = f2bf(tile[tx][ty + (i << 3)]);
        Xt[((size_t)p * BB + b) * CD + c] = v;
        int hh = p >> 6, ww = p & 63;
        int nw = ww >> 2, wd = ww & 3;
        int tp = ((hh << 2) + wd) * 128 + (b << 4) + nw;
        Xv[(size_t)tp * CD + c] = v;
    }
}

// ---- pool: Xp[(b*256+k)*512+c] = mean of 4x4 window (bf16 in/out) ----
__global__ __launch_bounds__(512)
void pool_from_xt(const unsigned short* __restrict__ Xt, unsigned short* __restrict__ Xp) {
    const int u = blockIdx.x;          // b*256+k
    const int c = threadIdx.x;         // 512
    const int b = u >> 8, k = u & 255;
    const int ph = k >> 4, pw = k & 15;
    float s = 0.f;
#pragma unroll
    for (int dy = 0; dy < 4; dy++)
#pragma unroll
        for (int dx = 0; dx < 4; dx++) {
            int p = ((ph << 2) + dy) * 64 + (pw << 2) + dx;
            s += bf2f(Xt[((size_t)p * BB + b) * CD + c]);
        }
    Xp[(size_t)u * CD + c] = f2bf(s * (1.f / 16.f));
}

// ---------------- MFMA GEMM core ----------------
// 128x128 tile, BK=64, 256 threads (4 waves 2x2), double-buffered LDS,
// global_load_lds width-16 staging. acc laid out per verified m89 C/D map.
__device__ __forceinline__ void stage_tile(const unsigned short* __restrict__ g,
                                           unsigned short* l, int K, int tid) {
#pragma unroll
    for (int i = 0; i < 4; i++) {
        int c  = i * 256 + tid;           // 16B chunk id, 0..1023
        int r  = c >> 3;                  // row 0..127
        int ko = (c & 7) << 3;            // k offset 0..56
        GL_LDS16(g + (size_t)r * K + ko, l + c * 8);
    }
}

__device__ __forceinline__ void gemm_core(const unsigned short* __restrict__ A,
                                          const unsigned short* __restrict__ W,
                                          int K, int row0, int col0, int tid,
                                          unsigned short* ldsA, unsigned short* ldsB,
                                          f32x4 acc[4][4]) {
    const int lane = tid & 63;
    const int wid  = tid >> 6;
    const int wr = wid >> 1, wc = wid & 1;
    const int lr = lane & 15, lg = lane >> 4;

    f32x4 zero = {0.f, 0.f, 0.f, 0.f};
#pragma unroll
    for (int m = 0; m < 4; m++)
#pragma unroll
        for (int n = 0; n < 4; n++) acc[m][n] = zero;

    const unsigned short* Ab = A + (size_t)row0 * K;
    const unsigned short* Wb = W + (size_t)col0 * K;

    stage_tile(Ab, ldsA, K, tid);
    stage_tile(Wb, ldsB, K, tid);
    __syncthreads();

    const int NTILES = K >> 6;
    int buf = 0;
    for (int t = 0; t < NTILES; t++) {
        if (t + 1 < NTILES) {
            stage_tile(Ab + ((t + 1) << 6), ldsA + ((buf ^ 1) << 13), K, tid);
            stage_tile(Wb + ((t + 1) << 6), ldsB + ((buf ^ 1) << 13), K, tid);
        }
#pragma unroll
        for (int kk = 0; kk < 2; kk++) {
            bf16x8 af[4], bfr[4];
#pragma unroll
            for (int m = 0; m < 4; m++)
                af[m] = *reinterpret_cast<const bf16x8*>(
                    ldsA + (buf << 13) + (wr * 64 + m * 16 + lr) * 64 + kk * 32 + lg * 8);
#pragma unroll
            for (int n = 0; n < 4; n++)
                bfr[n] = *reinterpret_cast<const bf16x8*>(
                    ldsB + (buf << 13) + (wc * 64 + n * 16 + lr) * 64 + kk * 32 + lg * 8);
#pragma unroll
            for (int m = 0; m < 4; m++)
#pragma unroll
                for (int n = 0; n < 4; n++)
                    acc[m][n] = __builtin_amdgcn_mfma_f32_16x16x32_bf16(af[m], bfr[n], acc[m][n], 0, 0, 0);
        }
        __syncthreads();
        buf ^= 1;
    }
}

// plain epilogue: optional fp32 + bf16 outputs, col mask for padded N
__global__ __launch_bounds__(256)
void gemm_mfma(const unsigned short* __restrict__ A, const unsigned short* __restrict__ W,
               const float* __restrict__ bias,
               float* __restrict__ Cf, unsigned short* __restrict__ Cb,
               int M, int K, int Nreal) {
    __shared__ unsigned short ldsA[2][128][64];
    __shared__ unsigned short ldsB[2][128][64];
    const int tid = threadIdx.x;
    const int lane = tid & 63, wid = tid >> 6;
    const int wr = wid >> 1, wc = wid & 1;
    const int lr = lane & 15, lg = lane >> 4;
    const int row0 = blockIdx.y << 7;
    const int col0 = blockIdx.x << 7;
    f32x4 acc[4][4];
    gemm_core(A, W, K, row0, col0, tid, &ldsA[0][0][0], &ldsB[0][0][0], acc);

#pragma unroll
    for (int n = 0; n < 4; n++) {
        int col = col0 + wc * 64 + n * 16 + lr;
        bool cok = col < Nreal;
        float bv = cok ? bias[col] : 0.f;
#pragma unroll
        for (int m = 0; m < 4; m++) {
            int row = row0 + wr * 64 + m * 16 + lg * 4;
            if (cok) {
#pragma unroll
                for (int i = 0; i < 4; i++) {
                    float v = acc[m][n][i] + bv;
                    if (Cf) Cf[(size_t)(row + i) * Nreal + col] = v;
                    if (Cb) Cb[(size_t)(row + i) * Nreal + col] = f2bf(v);
                }
            }
        }
    }
}

// segmented epilogue: col>>9 selects destination buffer (each [M][512] bf16)
__global__ __launch_bounds__(256)
void gemm_mfma_seg(const unsigned short* __restrict__ A, const unsigned short* __restrict__ W,
                   const float* __restrict__ bias,
                   unsigned short* __restrict__ D0, unsigned short* __restrict__ D1,
                   unsigned short* __restrict__ D2, int M, int K) {
    __shared__ unsigned short ldsA[2][128][64];
    __shared__ unsigned short ldsB[2][128][64];
    const int tid = threadIdx.x;
    const int lane = tid & 63, wid = tid >> 6;
    const int wr = wid >> 1, wc = wid & 1;
    const int lr = lane & 15, lg = lane >> 4;
    const int row0 = blockIdx.y << 7;
    const int col0 = blockIdx.x << 7;
    f32x4 acc[4][4];
    gemm_core(A, W, K, row0, col0, tid, &ldsA[0][0][0], &ldsB[0][0][0], acc);

#pragma unroll
    for (int n = 0; n < 4; n++) {
        int col = col0 + wc * 64 + n * 16 + lr;
        int seg = col >> 9, c2 = col & 511;
        unsigned short* dst = (seg == 0) ? D0 : ((seg == 1) ? D1 : D2);
        float bv = bias[col];
#pragma unroll
        for (int m = 0; m < 4; m++) {
            int row = row0 + wr * 64 + m * 16 + lg * 4;
#pragma unroll
            for (int i = 0; i < 4; i++)
                dst[(size_t)(row + i) * CD + c2] = f2bf(acc[m][n][i] + bv);
        }
    }
}

// vertical out-proj epilogue: rows are t' indices; store permuted to t order.
// t' = (hh*4+wd)*128 + b*16 + nw  ->  t = (hh*64 + nw*4 + wd)*8 + b
__global__ __launch_bounds__(256)
void gemm_mfma_vperm(const unsigned short* __restrict__ A, const unsigned short* __restrict__ W,
                     const float* __restrict__ bias,
                     float* __restrict__ Cf, unsigned short* __restrict__ Cb, int K) {
    __shared__ unsigned short ldsA[2][128][64];
    __shared__ unsigned short ldsB[2][128][64];
    const int tid = threadIdx.x;
    const int lane = tid & 63, wid = tid >> 6;
    const int wr = wid >> 1, wc = wid & 1;
    const int lr = lane & 15, lg = lane >> 4;
    const int row0 = blockIdx.y << 7;
    const int col0 = blockIdx.x << 7;
    f32x4 acc[4][4];
    gemm_core(A, W, K, row0, col0, tid, &ldsA[0][0][0], &ldsB[0][0][0], acc);

#pragma unroll
    for (int n = 0; n < 4; n++) {
        int col = col0 + wc * 64 + n * 16 + lr;
        float bv = bias[col];
#pragma unroll
        for (int m = 0; m < 4; m++) {
            int rbase = row0 + wr * 64 + m * 16 + lg * 4;
#pragma unroll
            for (int i = 0; i < 4; i++) {
                int r = rbase + i;
                int s = r >> 7, rem = r & 127;
                int b = rem >> 4, nw = rem & 15;
                int hh = s >> 2, wd = s & 3;
                int t = (((hh << 6) + (nw << 2) + wd) << 3) + b;
                float v = acc[m][n][i] + bv;
                Cf[(size_t)t * CD + col] = v;
                Cb[(size_t)t * CD + col] = f2bf(v);
            }
        }
    }
}

// ---------------- MFMA fused attention (Lk=256, D=64) ----------------
// token row address = q*QT + bi*QB (Q/O), k*KT + bi*KB (K/V); all bf16 [*][512]
// block: 512 threads = 8 waves; each wave owns 16 q-rows. O may alias Q.
__global__ __launch_bounds__(512)
void attn_mfma(const unsigned short* __restrict__ Q, const unsigned short* __restrict__ Kp,
               const unsigned short* __restrict__ Vp, unsigned short* __restrict__ O,
               int QT, int QB, int KT, int KB) {
    __shared__ unsigned short Kb[256][72];    // [k][d], +8 pad
    __shared__ unsigned short Vt[64][264];    // [d][k], +8 pad
    __shared__ unsigned short Pl[8][16][264]; // per-wave P tile
    const int tid  = threadIdx.x;
    const int lane = tid & 63;
    const int w    = tid >> 6;
    const int lr = lane & 15, lg = lane >> 4;
    const int bh = blockIdx.y, bi = bh >> 3, h = bh & 7;
    const int q0 = blockIdx.x << 7;

    // stage K and V^T
    for (int idx = tid; idx < 8192; idx += 512) {
        int k  = idx >> 5;
        int d2 = (idx & 31) << 1;
        size_t grow = ((size_t)k * KT + (size_t)bi * KB) * CD + h * HD + d2;
        unsigned int kv = *reinterpret_cast<const unsigned int*>(&Kp[grow]);
        unsigned int vv = *reinterpret_cast<const unsigned int*>(&Vp[grow]);
        Kb[k][d2]     = (unsigned short)(kv & 0xffff);
        Kb[k][d2 + 1] = (unsigned short)(kv >> 16);
        Vt[d2][k]     = (unsigned short)(vv & 0xffff);
        Vt[d2 + 1][k] = (unsigned short)(vv >> 16);
    }
    __syncthreads();

    // Q fragments (held in regs; enables in-place O)
    const int qrow = q0 + w * 16 + lr;
    const size_t qbase = ((size_t)qrow * QT + (size_t)bi * QB) * CD + h * HD;
    bf16x8 qf0 = *reinterpret_cast<const bf16x8*>(&Q[qbase + lg * 8]);
    bf16x8 qf1 = *reinterpret_cast<const bf16x8*>(&Q[qbase + 32 + lg * 8]);

    // S = Q K^T  (16 col-tiles of 16)
    f32x4 zero = {0.f, 0.f, 0.f, 0.f};
    f32x4 sacc[16];
#pragma unroll
    for (int t = 0; t < 16; t++) sacc[t] = zero;
#pragma unroll
    for (int t = 0; t < 16; t++) {
        bf16x8 kb0 = *reinterpret_cast<const bf16x8*>(&Kb[t * 16 + lr][lg * 8]);
        bf16x8 kb1 = *reinterpret_cast<const bf16x8*>(&Kb[t * 16 + lr][32 + lg * 8]);
        sacc[t] = __builtin_amdgcn_mfma_f32_16x16x32_bf16(qf0, kb0, sacc[t], 0, 0, 0);
        sacc[t] = __builtin_amdgcn_mfma_f32_16x16x32_bf16(qf1, kb1, sacc[t], 0, 0, 0);
    }
#pragma unroll
    for (int t = 0; t < 16; t++) sacc[t] = sacc[t] * 0.125f;

    // softmax over 256 cols; lane holds rows lg*4+i, cols t*16+lr
    float mrow[4] = {-1e30f, -1e30f, -1e30f, -1e30f};
#pragma unroll
    for (int t = 0; t < 16; t++)
#pragma unroll
        for (int i = 0; i < 4; i++) mrow[i] = fmaxf(mrow[i], sacc[t][i]);
#pragma unroll
    for (int i = 0; i < 4; i++) {
        mrow[i] = fmaxf(mrow[i], __shfl_xor(mrow[i], 1));
        mrow[i] = fmaxf(mrow[i], __shfl_xor(mrow[i], 2));
        mrow[i] = fmaxf(mrow[i], __shfl_xor(mrow[i], 4));
        mrow[i] = fmaxf(mrow[i], __shfl_xor(mrow[i], 8));
    }
    float ssum[4] = {0.f, 0.f, 0.f, 0.f};
#pragma unroll
    for (int t = 0; t < 16; t++)
#pragma unroll
        for (int i = 0; i < 4; i++) {
            float p = __expf(sacc[t][i] - mrow[i]);
            sacc[t][i] = p;
            ssum[i] += p;
        }
#pragma unroll
    for (int i = 0; i < 4; i++) {
        ssum[i] += __shfl_xor(ssum[i], 1);
        ssum[i] += __shfl_xor(ssum[i], 2);
        ssum[i] += __shfl_xor(ssum[i], 4);
        ssum[i] += __shfl_xor(ssum[i], 8);
    }
    float rinv[4];
#pragma unroll
    for (int i = 0; i < 4; i++) rinv[i] = 1.f / ssum[i];

    // write P (bf16) to this wave's LDS tile
#pragma unroll
    for (int t = 0; t < 16; t++)
#pragma unroll
        for (int i = 0; i < 4; i++)
            Pl[w][lg * 4 + i][t * 16 + lr] = f2bf(sacc[t][i] * rinv[i]);

    // O = P V  (4 d-tiles of 16, 8 k-steps of 32)
    f32x4 oacc[4];
#pragma unroll
    for (int n = 0; n < 4; n++) oacc[n] = zero;
#pragma unroll
    for (int ks = 0; ks < 8; ks++) {
        bf16x8 pa = *reinterpret_cast<const bf16x8*>(&Pl[w][lr][ks * 32 + lg * 8]);
#pragma unroll
        for (int n = 0; n < 4; n++) {
            bf16x8 vb = *reinterpret_cast<const bf16x8*>(&Vt[n * 16 + lr][ks * 32 + lg * 8]);
            oacc[n] = __builtin_amdgcn_mfma_f32_16x16x32_bf16(pa, vb, oacc[n], 0, 0, 0);
        }
    }
#pragma unroll
    for (int n = 0; n < 4; n++)
#pragma unroll
        for (int i = 0; i < 4; i++) {
            int qr2 = q0 + w * 16 + lg * 4 + i;
            size_t ob = ((size_t)qr2 * QT + (size_t)bi * QB) * CD + h * HD + n * 16 + lr;
            O[ob] = f2bf(oacc[n][i]);
        }
}

// ------ concat [HA|VA] -> attn_bchw + per-block partial sums (NO atomics) ------
// grid (32,16,8), block 32x8. Each block: 128 p x 32 c tile (4 sub-tiles).
__global__ __launch_bounds__(256)
void concat_stats(const float* __restrict__ HA, const float* __restrict__ VA,
                  const float* __restrict__ x, float* __restrict__ attn_out,
                  float* __restrict__ PS, float* __restrict__ PQ) {
    __shared__ float tile[32][33];
    __shared__ float wsum[4], wsq[4];
    const int b  = blockIdx.z;
    const int c0 = blockIdx.y << 5;
    const int tx = threadIdx.x;   // 32
    const int ty = threadIdx.y;   // 8
    const int tl = ty * 32 + tx;
    float lsum = 0.f, lsq = 0.f;

    for (int s = 0; s < 4; s++) {
        const int p0 = ((blockIdx.x << 2) + s) << 5;
#pragma unroll
        for (int i = 0; i < 4; i++) {
            int c = c0 + tx;
            int p = p0 + ty + (i << 3);
            size_t t = (size_t)p * BB + b;
            float v = (c < C1D) ? HA[t * C1D + c] : VA[t * C2D + (c - C1D)];
            tile[ty + (i << 3)][tx] = v;
        }
        __syncthreads();
#pragma unroll
        for (int i = 0; i < 4; i++) {
            int c = c0 + ty + (i << 3);
            int p = p0 + tx;
            size_t o = ((size_t)b * CD + c) * PP + p;
            float v = tile[tx][ty + (i << 3)];
            attn_out[o] = v;
            float r = v + x[o];
            lsum += r; lsq += r * r;
        }
        __syncthreads();
    }

    for (int off = 32; off; off >>= 1) {
        lsum += __shfl_xor(lsum, off);
        lsq  += __shfl_xor(lsq, off);
    }
    if ((tl & 63) == 0) { wsum[tl >> 6] = lsum; wsq[tl >> 6] = lsq; }
    __syncthreads();
    if (tl == 0) {
        const int bid = blockIdx.z * 512 + blockIdx.y * 32 + blockIdx.x;
        PS[bid] = wsum[0] + wsum[1] + wsum[2] + wsum[3];
        PQ[bid] = wsq[0] + wsq[1] + wsq[2] + wsq[3];
    }
}

// ---- final reduce: wave b sums its 512 partials -> mu, inv-std ----
__global__ __launch_bounds__(512)
void stats_final2(const float* __restrict__ PS, const float* __restrict__ PQ,
                  float* __restrict__ stats) {
    const int w    = threadIdx.x >> 6;   // 8 waves -> batch index
    const int lane = threadIdx.x & 63;
    float s = 0.f, q = 0.f;
    for (int i = lane; i < 512; i += 64) {
        s += PS[w * 512 + i];
        q += PQ[w * 512 + i];
    }
    for (int off = 32; off; off >>= 1) {
        s += __shfl_xor(s, off);
        q += __shfl_xor(q, off);
    }
    if (lane == 0) {
        const float n = (float)CD * (float)PP;
        float mu  = s / n;
        float var = q / n - mu * mu;
        stats[16 + w] = mu;
        stats[24 + w] = 1.f / sqrtf(var + 1e-5f);
    }
}

__global__ __launch_bounds__(256)
void norm_kernel(const float* __restrict__ attn, const float* __restrict__ x,
                 const float* __restrict__ stats, float* __restrict__ out) {
    size_t i = ((size_t)blockIdx.x * blockDim.x + threadIdx.x) * 4;
    int b = (int)(i >> 21);
    float mu  = stats[16 + b];
    float inv = stats[24 + b];
    const float4 a4 = *reinterpret_cast<const float4*>(attn + i);
    const float4 x4 = *reinterpret_cast<const float4*>(x + i);
    float4 r;
    r.x = (a4.x + x4.x - mu) * inv;
    r.y = (a4.y + x4.y - mu) * inv;
    r.z = (a4.z + x4.z - mu) * inv;
    r.w = (a4.w + x4.w - mu) * inv;
    *reinterpret_cast<float4*>(out + i) = r;
}

// ---------------- host launch ----------------
extern "C" void kernel_launch(void* const* d_in, const int* in_sizes, int n_in,
                              void* d_out, int out_size, void* d_ws, size_t ws_size,
                              hipStream_t stream) {
    const float* x     = (const float*)d_in[0];
    const float* hinw  = (const float*)d_in[1];
    const float* hinb  = (const float*)d_in[2];
    const float* houtw = (const float*)d_in[3];
    const float* houtb = (const float*)d_in[4];
    const float* vinw  = (const float*)d_in[5];
    const float* vinb  = (const float*)d_in[6];
    const float* voutw = (const float*)d_in[7];
    const float* voutb = (const float*)d_in[8];
    const float* hfcw  = (const float*)d_in[9];
    const float* hfcb  = (const float*)d_in[10];
    const float* vfcw  = (const float*)d_in[11];
    const float* vfcb  = (const float*)d_in[12];

    char* wsb = (char*)d_ws;
    unsigned short* R0  = (unsigned short*)(wsb);               // Xt -> HAXB -> KVb
    unsigned short* R1  = (unsigned short*)(wsb + 33554432);    // Q/O both branches
    unsigned short* R2  = (unsigned short*)(wsb + 67108864);    // Xv -> VAXB
    unsigned short* R3  = (unsigned short*)(wsb + 100663296);   // VVb
    unsigned short* XP  = (unsigned short*)(wsb + 134217728);
    unsigned short* KHb = (unsigned short*)(wsb + 136314880);
    unsigned short* VHb = (unsigned short*)(wsb + 138412032);
    float* HA = (float*)(wsb + 140509184);                       // [32768][358]
    float* VA = (float*)(wsb + 187432960);                       // [32768][154]
    unsigned short* Whin  = (unsigned short*)(wsb + 207618048);  // [1536][512]
    unsigned short* Whout = Whin + 786432;                       // [512][512]
    unsigned short* Wvin  = Whout + 262144;                      // [1536][512]
    unsigned short* Wvout = Wvin + 786432;                       // [512][512]
    unsigned short* Whfc  = Wvout + 262144;                      // [384][512] padded
    unsigned short* Wvfc  = Whfc + 196608;                       // [256][512] padded
    float* STATS = (float*)(wsb + 212467712);                    // 32 floats
    float* PS    = (float*)(wsb + 212471808);                    // 4096 floats
    float* PQ    = PS + 4096;                                    // 4096 floats

    float* out_res = (float*)d_out;
    float* out_hax = out_res + 16777216;
    float* out_vax = out_res + 33554432;
    float* out_att = out_res + 50331648;

    // ---- weights (1 dispatch) ----
    cast_all<<<9472, 256, 0, stream>>>(hinw, houtw, vinw, voutw, hfcw, vfcw,
                                       Whin, Whout, Wvin, Wvout, Whfc, Wvfc);

    const dim3 tb(32, 8, 1);

    // ---- shared input prep: one pass over x ----
    transpose_both<<<dim3(128, 16, 8), tb, 0, stream>>>(x, R0, R2);       // Xt + Xv
    pool_from_xt<<<2048, 512, 0, stream>>>(R0, XP);

    // ---- horizontal branch ----
    gemm_mfma<<<dim3(4, 256), 256, 0, stream>>>(R0, Whin, hinb, nullptr, R1, NT, CD, CD);      // QH
    gemm_mfma_seg<<<dim3(8, 16), 256, 0, stream>>>(XP, Whin + 262144, hinb + 512,
                                                   KHb, VHb, nullptr, 2048, CD);               // KH|VH
    attn_mfma<<<dim3(32, 64), 512, 0, stream>>>(R1, KHb, VHb, R1, BB, 1, 1, 256);              // OH in-place
    gemm_mfma<<<dim3(4, 256), 256, 0, stream>>>(R1, Whout, houtb, out_hax, R0, NT, CD, CD);    // ha_x (+bf16)
    gemm_mfma<<<dim3(3, 256), 256, 0, stream>>>(R0, Whfc, hfcb, HA, nullptr, NT, CD, C1D);     // HA

    // ---- vertical branch ----
    gemm_mfma_seg<<<dim3(12, 256), 256, 0, stream>>>(R2, Wvin, vinb, R1, R0, R3, NT, CD);      // QV|KV|VV
    attn_mfma<<<dim3(2, 1024), 512, 0, stream>>>(R1, R0, R3, R1, 128, 1, 128, 1);              // OV in-place
    gemm_mfma_vperm<<<dim3(4, 256), 256, 0, stream>>>(R1, Wvout, voutb, out_vax, R2, CD);      // va_x (+bf16), permuted
    gemm_mfma<<<dim3(2, 256), 256, 0, stream>>>(R2, Wvfc, vfcb, VA, nullptr, NT, CD, C2D);     // VA

    // ---- concat + residual + layernorm (two-stage reduction) ----
    concat_stats<<<dim3(32, 16, 8), tb, 0, stream>>>(HA, VA, x, out_att, PS, PQ);
    stats_final2<<<1, 512, 0, stream>>>(PS, PQ, STATS);
    norm_kernel<<<16384, 256, 0, stream>>>(out_att, x, STATS, out_res);
}